// Round 16
// baseline (269.045 us; speedup 1.0000x reference)
//
#include <hip/hip_runtime.h>

namespace {
constexpr int Wd = 160, Hd = 192, Dd = 160, Bd = 2;
constexpr int HW = Hd * Wd;
constexpr int ROWS_OUT = 8;                // output rows per wave-tile
constexpr int ROWS_LDS = 10;               // staged rows incl. h-halo
constexpr int TSTRIPS = 8;                 // float4 strips per tile row (32 w)
constexpr int TILE_W = 32;
constexpr int RS = 36;                     // LDS row stride (floats) -> bank stagger
constexpr int WTILES = Wd / TILE_W;        // 5
constexpr int HTILES = Hd / ROWS_OUT;      // 24
constexpr int TASKS = 2 * ROWS_LDS * TSTRIPS;  // 160 staging tasks per wave
constexpr int DCHUNK = 10;
constexpr int NCHUNK = Dd / DCHUNK;        // 16
constexpr int TILES_X = HTILES * WTILES;   // 120 wave-tiles per (d,b) slice
constexpr int BLOCKS_X = TILES_X / 4;      // 30 blocks of 4 waves
constexpr float EPS = 1e-8f;
}

using v4f = __attribute__((ext_vector_type(4))) float;

__device__ __forceinline__ float dpp_up1(float v) {   // lane i <- lane i-1
  return __int_as_float(__builtin_amdgcn_update_dpp(
      0, __float_as_int(v), 0x138, 0xF, 0xF, true));  // wave_shr:1
}
__device__ __forceinline__ float dpp_dn1(float v) {   // lane i <- lane i+1
  return __int_as_float(__builtin_amdgcn_update_dpp(
      0, __float_as_int(v), 0x130, 0xF, 0xF, true));  // wave_shl:1
}

__global__ __launch_bounds__(256, 3) void sobel_loss_kernel(
    const float* __restrict__ pred, const float* __restrict__ targ,
    float* __restrict__ out) {
  // per-wave private slabs: sw = [1,2,1]_w * x, dw = [-1,0,1]_w * x
  __shared__ float lsw[4][2][ROWS_LDS][RS];   // 11.5 KB
  __shared__ float ldw[4][2][ROWS_LDS][RS];   // 11.5 KB
  const int tid = threadIdx.x;
  const int lane = tid & 63;
  const int wv = tid >> 6;
  const int tileIdx = blockIdx.x * 4 + wv;
  const int wt = tileIdx % WTILES;
  const int ht = tileIdx / WTILES;
  const int h0 = ht * ROWS_OUT;
  const int wb = wt * TILE_W;
  const int d0 = blockIdx.y * DCHUNK;
  const size_t volOff = (size_t)blockIdx.z * Dd * HW;
  const float* pb = pred + volOff;
  const float* tb = targ + volOff;

  // ---- staging task decode (2.5 tasks/lane, loop-invariant) ----
  const float* gs[3];
  float* psw[3];
  float* pdw[3];
  bool sok[3], rok[3], zL[3], zR[3], pL[3], pR[3];
#pragma unroll
  for (int u = 0; u < 3; ++u) {
    const int i = lane + 64 * u;
    const bool ok = (i < TASKS);
    const int ic = ok ? i : 0;
    const int t_ = ic / (ROWS_LDS * TSTRIPS);
    const int rem = ic - t_ * (ROWS_LDS * TSTRIPS);
    const int r = rem / TSTRIPS, s = rem & (TSTRIPS - 1);
    const int hh = h0 - 1 + r;
    const bool rv = ok && ((unsigned)hh < (unsigned)Hd);
    sok[u] = ok;
    rok[u] = rv;
    zL[u] = (s == 0) && (wb == 0);
    zR[u] = (s == TSTRIPS - 1) && (wb + TILE_W >= Wd);
    pL[u] = ok && (s == 0) && (wb > 0);
    pR[u] = ok && (s == TSTRIPS - 1) && (wb + TILE_W < Wd);
    gs[u] = (t_ ? tb : pb) + (size_t)(rv ? hh : 0) * Wd + wb + s * 4;
    psw[u] = &lsw[wv][t_][r][s * 4];
    pdw[u] = &ldw[wv][t_][r][s * 4];
  }

  float4 m[3];
  float hl[3], hr[3];
  auto GLOAD = [&](int d) {   // float4 + exec-masked edge scalars
    const bool dok = (unsigned)d < (unsigned)Dd;
    const size_t so = (size_t)d * HW;
#pragma unroll
    for (int u = 0; u < 3; ++u) {
      float4 v = make_float4(0.f, 0.f, 0.f, 0.f);
      float a = 0.f, b = 0.f;
      if (dok && rok[u]) {
        v = *reinterpret_cast<const float4*>(gs[u] + so);
        if (pL[u]) a = gs[u][so - 1];
        if (pR[u]) b = gs[u][so + 4];
      }
      m[u] = v; hl[u] = a; hr[u] = b;
    }
  };

  auto STAGE = [&]() {   // w-conv once per staged row, write sw/dw to own slab
#pragma unroll
    for (int u = 0; u < 3; ++u) {
      float xl = dpp_up1(m[u].w);
      float xr = dpp_dn1(m[u].x);
      if (zL[u]) xl = 0.f;
      if (pL[u]) xl = hl[u];
      if (zR[u]) xr = 0.f;
      if (pR[u]) xr = hr[u];
      const float x0 = xl, x1 = m[u].x, x2 = m[u].y, x3 = m[u].z,
                  x4 = m[u].w, x5 = xr;
      float4 swv, dwv;
      swv.x = fmaf(2.f, x1, x0 + x2);  dwv.x = x2 - x0;
      swv.y = fmaf(2.f, x2, x1 + x3);  dwv.y = x3 - x1;
      swv.z = fmaf(2.f, x3, x2 + x4);  dwv.z = x4 - x2;
      swv.w = fmaf(2.f, x4, x3 + x5);  dwv.w = x5 - x3;
      if (sok[u]) {
        *reinterpret_cast<float4*>(psw[u]) = swv;
        *reinterpret_cast<float4*>(pdw[u]) = dwv;
      }
    }
  };

  // ---- compute decode: 64 lanes = 8 rows x 8 strips, 1 output float4/lane
  const int cr = lane >> 3;
  const int cs4 = (lane & 7) * 4;

  // rolling state [slot][tensor] as 4-wide vectors -> v_pk_* math
  v4f A[3][2], B[3][2], C[3][2];

  auto HCONV = [&](int slot) {
#pragma unroll
    for (int t_ = 0; t_ < 2; ++t_) {
      const v4f sm = *reinterpret_cast<const v4f*>(&lsw[wv][t_][cr][cs4]);
      const v4f s0 = *reinterpret_cast<const v4f*>(&lsw[wv][t_][cr + 1][cs4]);
      const v4f sp = *reinterpret_cast<const v4f*>(&lsw[wv][t_][cr + 2][cs4]);
      const v4f dm = *reinterpret_cast<const v4f*>(&ldw[wv][t_][cr][cs4]);
      const v4f dd = *reinterpret_cast<const v4f*>(&ldw[wv][t_][cr + 1][cs4]);
      const v4f dp = *reinterpret_cast<const v4f*>(&ldw[wv][t_][cr + 2][cs4]);
      A[slot][t_] = s0 * 2.f + (sm + sp);
      B[slot][t_] = dd * 2.f + (dm + dp);
      C[slot][t_] = sp - sm;
    }
  };

  v4f accv = {0.f, 0.f, 0.f, 0.f};

  // ---- prologue: wave-synchronous LDS, no runtime barriers ----
  GLOAD(d0 - 1);
  STAGE(); GLOAD(d0);
  HCONV(0);
  __builtin_amdgcn_sched_barrier(0);
  STAGE(); GLOAD(d0 + 1);
  HCONV(1);
  __builtin_amdgcn_sched_barrier(0);

  // ---- main loop, fully unrolled, zero runtime barriers;
  //      sched_barrier(0) pins per-iteration live ranges (anti-hoist) ----
#pragma unroll
  for (int k = 0; k < DCHUNK; ++k) {
    __builtin_amdgcn_sched_barrier(0);
    STAGE();                               // slab <- slice d0+1+k
    if (k < DCHUNK - 1) GLOAD(d0 + 2 + k); // issue next; consumed next iter
    const int i0 = k % 3, i1 = (k + 1) % 3, i2 = (k + 2) % 3;
    HCONV(i2);                             // state <- slice d0+1+k
    const v4f gx0 = B[i1][0] * 2.f + (B[i0][0] + B[i2][0]);
    const v4f gy0 = C[i1][0] * 2.f + (C[i0][0] + C[i2][0]);
    const v4f gz0 = A[i2][0] - A[i0][0];
    const v4f q0 = gx0 * gx0 + gy0 * gy0 + gz0 * gz0 + EPS;
    const v4f gx1 = B[i1][1] * 2.f + (B[i0][1] + B[i2][1]);
    const v4f gy1 = C[i1][1] * 2.f + (C[i0][1] + C[i2][1]);
    const v4f gz1 = A[i2][1] - A[i0][1];
    const v4f q1 = gx1 * gx1 + gy1 * gy1 + gz1 * gz1 + EPS;
    v4f dd_;
#pragma unroll
    for (int j = 0; j < 4; ++j)
      dd_[j] = __builtin_amdgcn_sqrtf(q0[j]) - __builtin_amdgcn_sqrtf(q1[j]);
#pragma unroll
    for (int j = 0; j < 4; ++j) dd_[j] = fabsf(dd_[j]);
    accv += dd_;
  }

  // ---- reduction: wave shfl -> LDS -> one atomic per block ----
  float sred = accv.x + accv.y + accv.z + accv.w;
#pragma unroll
  for (int off = 32; off > 0; off >>= 1) sred += __shfl_down(sred, off, 64);
  __shared__ float wsum[4];
  if (lane == 0) wsum[wv] = sred;
  __syncthreads();
  if (tid == 0) {
    atomicAdd(out, (wsum[0] + wsum[1] + wsum[2] + wsum[3]) *
                       (1.0f / (float)((size_t)Bd * Dd * Hd * Wd)));
  }
}

extern "C" void kernel_launch(void* const* d_in, const int* in_sizes, int n_in,
                              void* d_out, int out_size, void* d_ws, size_t ws_size,
                              hipStream_t stream) {
  const float* pred = (const float*)d_in[0];
  const float* targ = (const float*)d_in[1];
  float* out = (float*)d_out;
  (void)in_sizes; (void)n_in; (void)out_size; (void)d_ws; (void)ws_size;

  hipMemsetAsync(out, 0, sizeof(float), stream);
  dim3 grid(BLOCKS_X, NCHUNK, Bd);
  sobel_loss_kernel<<<grid, 256, 0, stream>>>(pred, targ, out);
}

// Round 17
// 80.634 us; speedup vs baseline: 3.3366x; 3.3366x over previous
//
#include <hip/hip_runtime.h>

namespace {
constexpr int Wd = 160, Hd = 192, Dd = 160, Bd = 2;
constexpr int HW = Hd * Wd;
constexpr int ROWS_OUT = 8, ROWS_LDS = 10, TSTRIPS = 8, TILE_W = 32;
constexpr int RS = 36;                     // slab row stride -> uniform b128 banks
constexpr int WTILES = Wd / TILE_W;        // 5
constexpr int HTILES = Hd / ROWS_OUT;      // 24
constexpr int WAVES_PB = 3;                // 192 threads/block
constexpr int TILES_X = HTILES * WTILES;   // 120 wave-tiles
constexpr int BLOCKS_X = TILES_X / WAVES_PB;  // 40
constexpr int TASKS = 2 * ROWS_LDS * TSTRIPS; // 160 staging tasks per wave
constexpr int DCHUNK = 10;
constexpr int NCHUNK = Dd / DCHUNK;        // 16 -> grid 40*16*2 = 1280 = 5/CU
constexpr float EPS = 1e-8f;
}

using v4f = __attribute__((ext_vector_type(4))) float;

__device__ __forceinline__ float dpp_up1(float v) {   // lane i <- lane i-1
  return __int_as_float(__builtin_amdgcn_update_dpp(
      0, __float_as_int(v), 0x138, 0xF, 0xF, true));  // wave_shr:1
}
__device__ __forceinline__ float dpp_dn1(float v) {   // lane i <- lane i+1
  return __int_as_float(__builtin_amdgcn_update_dpp(
      0, __float_as_int(v), 0x130, 0xF, 0xF, true));  // wave_shl:1
}

// One tensor's slice absorb: read own slab rows, incremental d-state update.
// UB = B(s-2)+2B(s-1); BL = B(s-1); APAR = A(s-2) (parity reg). 1 mov (APAR).
#define TB(TI, UB, UC, BL, CL, APAR, QV, DO_EMIT)                             \
  {                                                                           \
    const v4f sm = *(const v4f*)&lsw[wv][TI][cr][cs4];                        \
    const v4f s0 = *(const v4f*)&lsw[wv][TI][cr + 1][cs4];                    \
    const v4f sp = *(const v4f*)&lsw[wv][TI][cr + 2][cs4];                    \
    const v4f dm = *(const v4f*)&ldw[wv][TI][cr][cs4];                        \
    const v4f dd = *(const v4f*)&ldw[wv][TI][cr + 1][cs4];                    \
    const v4f dp = *(const v4f*)&ldw[wv][TI][cr + 2][cs4];                    \
    const v4f ta = s0 * 2.f + (sm + sp);                                      \
    const v4f tb = dd * 2.f + (dm + dp);                                      \
    const v4f tc = sp - sm;                                                   \
    if (DO_EMIT) {                                                            \
      const v4f gx = UB + tb;                                                 \
      const v4f gy = UC + tc;                                                 \
      const v4f gz = ta - APAR;                                               \
      QV = gx * gx + gy * gy + gz * gz + EPS;                                 \
    }                                                                         \
    UB = tb * 2.f + BL;  BL = tb;                                             \
    UC = tc * 2.f + CL;  CL = tc;                                             \
    APAR = ta;                                                                \
  }

// Full body: both tensors + emit of |pm - tm|
#define BODY(APARP, APART, DO_EMIT)                                           \
  {                                                                           \
    v4f qP, qT;                                                               \
    TB(0, uBP, uCP, bLP, cLP, APARP, qP, DO_EMIT)                             \
    TB(1, uBT, uCT, bLT, cLT, APART, qT, DO_EMIT)                             \
    if (DO_EMIT) {                                                            \
      v4f dd_;                                                                \
      _Pragma("unroll") for (int j = 0; j < 4; ++j)                           \
          dd_[j] = __builtin_amdgcn_sqrtf(qP[j]) -                            \
                   __builtin_amdgcn_sqrtf(qT[j]);                             \
      _Pragma("unroll") for (int j = 0; j < 4; ++j) dd_[j] = fabsf(dd_[j]);   \
      accv += dd_;                                                            \
    }                                                                         \
  }

__global__ __launch_bounds__(192) void sobel_loss_kernel(
    const float* __restrict__ pred, const float* __restrict__ targ,
    float* __restrict__ out) {
  // per-wave private slabs: sw = [1,2,1]_w * x, dw = [-1,0,1]_w * x
  __shared__ float lsw[WAVES_PB][2][ROWS_LDS][RS];   // 8.6 KB
  __shared__ float ldw[WAVES_PB][2][ROWS_LDS][RS];   // 8.6 KB
  const int tid = threadIdx.x;
  const int lane = tid & 63;
  const int wv = tid >> 6;                 // 0..2
  const int tileIdx = blockIdx.x * WAVES_PB + wv;
  const int wt = tileIdx % WTILES;
  const int ht = tileIdx / WTILES;
  const int h0 = ht * ROWS_OUT;
  const int wb = wt * TILE_W;
  const int d0 = blockIdx.y * DCHUNK;
  const size_t volOff = (size_t)blockIdx.z * Dd * HW;
  const float* pb = pred + volOff;
  const float* tb = targ + volOff;

  // ---- staging task decode (2.5 tasks/lane, loop-invariant) ----
  const float* gs[3];
  float* psw[3];
  float* pdw[3];
  bool sok[3], rok[3], zL[3], zR[3], pL[3], pR[3];
#pragma unroll
  for (int u = 0; u < 3; ++u) {
    const int i = lane + 64 * u;
    const bool ok = (i < TASKS);
    const int ic = ok ? i : 0;
    const int t_ = ic / (ROWS_LDS * TSTRIPS);
    const int rem = ic - t_ * (ROWS_LDS * TSTRIPS);
    const int r = rem / TSTRIPS, s = rem & (TSTRIPS - 1);
    const int hh = h0 - 1 + r;
    const bool rv = ok && ((unsigned)hh < (unsigned)Hd);
    sok[u] = ok;
    rok[u] = rv;
    zL[u] = (s == 0) && (wb == 0);
    zR[u] = (s == TSTRIPS - 1) && (wb + TILE_W >= Wd);
    pL[u] = ok && (s == 0) && (wb > 0);
    pR[u] = ok && (s == TSTRIPS - 1) && (wb + TILE_W < Wd);
    gs[u] = (t_ ? tb : pb) + (size_t)(rv ? hh : 0) * Wd + wb + s * 4;
    psw[u] = &lsw[wv][t_][r][s * 4];
    pdw[u] = &ldw[wv][t_][r][s * 4];
  }

  float4 m[3];
  float hl[3], hr[3];
  auto GLOAD = [&](int d) {   // float4 + exec-masked edge scalars
    const bool dok = (unsigned)d < (unsigned)Dd;
    const size_t so = (size_t)d * HW;
#pragma unroll
    for (int u = 0; u < 3; ++u) {
      float4 v = make_float4(0.f, 0.f, 0.f, 0.f);
      float a = 0.f, b = 0.f;
      if (dok && rok[u]) {
        v = *reinterpret_cast<const float4*>(gs[u] + so);
        if (pL[u]) a = gs[u][so - 1];
        if (pR[u]) b = gs[u][so + 4];
      }
      m[u] = v; hl[u] = a; hr[u] = b;
    }
  };

  auto STAGE = [&]() {   // w-conv once per staged row, write sw/dw to own slab
#pragma unroll
    for (int u = 0; u < 3; ++u) {
      float xl = dpp_up1(m[u].w);
      float xr = dpp_dn1(m[u].x);
      if (zL[u]) xl = 0.f;
      if (pL[u]) xl = hl[u];
      if (zR[u]) xr = 0.f;
      if (pR[u]) xr = hr[u];
      const float x0 = xl, x1 = m[u].x, x2 = m[u].y, x3 = m[u].z,
                  x4 = m[u].w, x5 = xr;
      float4 swv, dwv;
      swv.x = fmaf(2.f, x1, x0 + x2);  dwv.x = x2 - x0;
      swv.y = fmaf(2.f, x2, x1 + x3);  dwv.y = x3 - x1;
      swv.z = fmaf(2.f, x3, x2 + x4);  dwv.z = x4 - x2;
      swv.w = fmaf(2.f, x4, x3 + x5);  dwv.w = x5 - x3;
      if (sok[u]) {
        *reinterpret_cast<float4*>(psw[u]) = swv;
        *reinterpret_cast<float4*>(pdw[u]) = dwv;
      }
    }
  };

  // ---- compute decode: 64 lanes = 8 rows x 8 strips, 1 output float4/lane
  const int cr = lane >> 3;
  const int cs4 = (lane & 7) * 4;

  // incremental d-state: 6 v4f per tensor (48 scalar regs total)
  v4f uBP = {0.f,0.f,0.f,0.f}, uCP = uBP, bLP = uBP, cLP = uBP,
      aEvP = uBP, aOdP = uBP;
  v4f uBT = uBP, uCT = uBP, bLT = uBP, cLT = uBP, aEvT = uBP, aOdT = uBP;
  v4f accv = {0.f, 0.f, 0.f, 0.f};

  // ---- prologue: absorb slices d0-1 (even role) and d0 (odd role) ----
  GLOAD(d0 - 1);
  STAGE();                 // LDS <- d0-1
  GLOAD(d0);
  BODY(aEvP, aEvT, false)  // absorb d0-1
  STAGE();                 // LDS <- d0
  GLOAD(d0 + 1);
  BODY(aOdP, aOdT, false)  // absorb d0

  // ---- main loop: 2 bodies/iter, zero barriers (wave-synchronous LDS) ----
#pragma unroll 1
  for (int s = d0 + 1; s <= d0 + DCHUNK; s += 2) {
    // even body: slice s, emits s-1
    STAGE();                               // LDS <- slice s
    GLOAD(s + 1);                          // m <- slice s+1
    BODY(aEvP, aEvT, true)
    // odd body: slice s+1, emits s
    STAGE();                               // LDS <- slice s+1
    if (s + 2 <= d0 + DCHUNK) GLOAD(s + 2);
    BODY(aOdP, aOdT, true)
  }

  // ---- reduction: wave shfl -> one atomic per wave (no barrier) ----
  float sred = accv.x + accv.y + accv.z + accv.w;
#pragma unroll
  for (int off = 32; off > 0; off >>= 1) sred += __shfl_down(sred, off, 64);
  if (lane == 0) {
    atomicAdd(out, sred * (1.0f / (float)((size_t)Bd * Dd * Hd * Wd)));
  }
}

extern "C" void kernel_launch(void* const* d_in, const int* in_sizes, int n_in,
                              void* d_out, int out_size, void* d_ws, size_t ws_size,
                              hipStream_t stream) {
  const float* pred = (const float*)d_in[0];
  const float* targ = (const float*)d_in[1];
  float* out = (float*)d_out;
  (void)in_sizes; (void)n_in; (void)out_size; (void)d_ws; (void)ws_size;

  hipMemsetAsync(out, 0, sizeof(float), stream);
  dim3 grid(BLOCKS_X, NCHUNK, Bd);
  sobel_loss_kernel<<<grid, 192, 0, stream>>>(pred, targ, out);
}

// Round 18
// 38.108 us; speedup vs baseline: 7.0601x; 2.1160x over previous
//
#include <hip/hip_runtime.h>

namespace {
constexpr int Wd = 160, Hd = 192, Dd = 160, Bd = 2;
constexpr int HW = Hd * Wd;
constexpr int THREADS = 256;               // 4 waves
constexpr int ROWS_OUT = 6;                // output rows per block
constexpr int ROWS_LDS = 8;                // staged rows incl. h-halo
constexpr int RS = 164;                    // LDS row stride (floats)
constexpr int STRIPS = 40;                 // float4 strips per row
constexpr int CTHREADS = ROWS_OUT * STRIPS;   // 240 compute threads
constexpr int TASKS = 2 * ROWS_LDS * STRIPS;  // 640 staging tasks
constexpr int DCHUNK = 10;                 // grid 1024 (proven best)
constexpr int NCHUNK = Dd / DCHUNK;        // 16
constexpr int RGROUPS = Hd / ROWS_OUT;     // 32
constexpr float EPS = 1e-8f;
}

using v4f = __attribute__((ext_vector_type(4))) float;

__device__ __forceinline__ float dpp_up1(float v) {   // lane i <- lane i-1
  return __int_as_float(__builtin_amdgcn_update_dpp(
      0, __float_as_int(v), 0x138, 0xF, 0xF, true));  // wave_shr:1
}
__device__ __forceinline__ float dpp_dn1(float v) {   // lane i <- lane i+1
  return __int_as_float(__builtin_amdgcn_update_dpp(
      0, __float_as_int(v), 0x130, 0xF, 0xF, true));  // wave_shl:1
}

__global__ __launch_bounds__(THREADS) void sobel_loss_kernel(
    const float* __restrict__ pred, const float* __restrict__ targ,
    float* __restrict__ out) {
  // staged separable row partials: sw = [1,2,1]_w * x, dw = [-1,0,1]_w * x
  __shared__ float lsw[2][ROWS_LDS][RS];   // 10.5 KB
  __shared__ float ldw[2][ROWS_LDS][RS];   // 10.5 KB
  const int tid = threadIdx.x;
  const int lane = tid & 63;
  const int h0 = blockIdx.x * ROWS_OUT;
  const int d0 = blockIdx.y * DCHUNK;
  const size_t volOff = (size_t)blockIdx.z * Dd * HW;
  const float* pb = pred + volOff;
  const float* tb = targ + volOff;

  // ---- staging task decode (2.5 tasks/thread, loop-invariant) ----
  const float* gs[3];
  float* psw[3];
  float* pdw[3];
  bool sok[3], rok[3], zL[3], zR[3], pL[3], pR[3];
#pragma unroll
  for (int u = 0; u < 3; ++u) {
    const int i = tid + 256 * u;
    const bool ok = (i < TASKS);
    const int ic = ok ? i : 0;
    const int t_ = ic / (ROWS_LDS * STRIPS);
    const int rem = ic - t_ * (ROWS_LDS * STRIPS);
    const int r8 = rem / STRIPS, s = rem - r8 * STRIPS;
    const int hh = h0 - 1 + r8;
    const bool rv = ok && ((unsigned)hh < (unsigned)Hd);
    sok[u] = ok;
    rok[u] = rv;
    zL[u] = (s == 0);
    zR[u] = (s == STRIPS - 1);
    pL[u] = ok && (lane == 0) && (s != 0);
    pR[u] = ok && (lane == 63) && (s != STRIPS - 1);
    gs[u] = (t_ ? tb : pb) + (size_t)(rv ? hh : 0) * Wd + s * 4;
    psw[u] = &lsw[t_][r8][s * 4];
    pdw[u] = &ldw[t_][r8][s * 4];
  }

  float4 m[3];
  float hl[3], hr[3];
  auto GLOAD = [&](int d) {   // float4-only + <=2 exec-masked scalars per wave
    const bool dok = (unsigned)d < (unsigned)Dd;
    const size_t so = (size_t)d * HW;
#pragma unroll
    for (int u = 0; u < 3; ++u) {
      float4 v = make_float4(0.f, 0.f, 0.f, 0.f);
      float a = 0.f, b = 0.f;
      if (dok && rok[u]) {
        v = *reinterpret_cast<const float4*>(gs[u] + so);
        if (pL[u]) a = gs[u][so - 1];
        if (pR[u]) b = gs[u][so + 4];
      }
      m[u] = v; hl[u] = a; hr[u] = b;
    }
  };

  auto STAGE = [&]() {   // w-conv once per input row, write sw/dw to LDS
#pragma unroll
    for (int u = 0; u < 3; ++u) {
      float xl = dpp_up1(m[u].w);          // lane-1 holds x[4s-4..4s-1]
      float xr = dpp_dn1(m[u].x);          // lane+1 holds x[4s+4..4s+7]
      if (zL[u]) xl = 0.f;
      if (pL[u]) xl = hl[u];
      if (zR[u]) xr = 0.f;
      if (pR[u]) xr = hr[u];
      const float x0 = xl, x1 = m[u].x, x2 = m[u].y, x3 = m[u].z,
                  x4 = m[u].w, x5 = xr;
      float4 swv, dwv;
      swv.x = fmaf(2.f, x1, x0 + x2);  dwv.x = x2 - x0;
      swv.y = fmaf(2.f, x2, x1 + x3);  dwv.y = x3 - x1;
      swv.z = fmaf(2.f, x3, x2 + x4);  dwv.z = x4 - x2;
      swv.w = fmaf(2.f, x4, x3 + x5);  dwv.w = x5 - x3;
      if (sok[u]) {
        *reinterpret_cast<float4*>(psw[u]) = swv;
        *reinterpret_cast<float4*>(pdw[u]) = dwv;
      }
    }
  };

  // ---- compute decode: output row cr (0..5), strip cs (0..39) ----
  const int cr = tid / STRIPS;
  const int cs4 = (tid - cr * STRIPS) * 4;
  const bool is_c = (tid < CTHREADS);

  // rolling state [slot][tensor] as 4-wide vectors -> v_pk_* math
  v4f A[3][2], B[3][2], C[3][2];

  auto HCONV = [&](int slot) {
#pragma unroll
    for (int t_ = 0; t_ < 2; ++t_) {
      const v4f sm = *reinterpret_cast<const v4f*>(&lsw[t_][cr][cs4]);
      const v4f s0 = *reinterpret_cast<const v4f*>(&lsw[t_][cr + 1][cs4]);
      const v4f sp = *reinterpret_cast<const v4f*>(&lsw[t_][cr + 2][cs4]);
      const v4f dm = *reinterpret_cast<const v4f*>(&ldw[t_][cr][cs4]);
      const v4f dd = *reinterpret_cast<const v4f*>(&ldw[t_][cr + 1][cs4]);
      const v4f dp = *reinterpret_cast<const v4f*>(&ldw[t_][cr + 2][cs4]);
      A[slot][t_] = s0 * 2.f + (sm + sp);
      B[slot][t_] = dd * 2.f + (dm + dp);
      C[slot][t_] = sp - sm;
    }
  };

  v4f accv = {0.f, 0.f, 0.f, 0.f};

  // ---- prologue: slices d0-1 (slot0) and d0 (slot1) ----
  // loads are always issued AFTER a barrier so the barrier-drain (s_waitcnt
  // vmcnt(0) before s_barrier) lands a full compute phase after issue.
  GLOAD(d0 - 1);
  STAGE();
  __syncthreads();              // drains nothing: d0-1 loads consumed by STAGE
  GLOAD(d0);                    // issue post-barrier
  if (is_c) HCONV(0);
  __syncthreads();              // drain of GLOAD(d0) covered by HCONV
  STAGE();
  __syncthreads();
  GLOAD(d0 + 1);
  if (is_c) HCONV(1);
  __syncthreads();

  // ---- main loop, fully unrolled: output slice d0+k ----
#pragma unroll
  for (int k = 0; k < DCHUNK; ++k) {
    STAGE();                    // consume loads issued last iteration
    __syncthreads();            // barrier 1: no outstanding VMEM -> free drain
    if (k < DCHUNK - 1) GLOAD(d0 + 2 + k);  // issue AFTER barrier
    const int i0 = k % 3, i1 = (k + 1) % 3, i2 = (k + 2) % 3;
    if (is_c) {
      HCONV(i2);                // covering work for the in-flight loads
      const v4f gx0 = B[i1][0] * 2.f + (B[i0][0] + B[i2][0]);
      const v4f gy0 = C[i1][0] * 2.f + (C[i0][0] + C[i2][0]);
      const v4f gz0 = A[i2][0] - A[i0][0];
      const v4f q0 = gx0 * gx0 + gy0 * gy0 + gz0 * gz0 + EPS;
      const v4f gx1 = B[i1][1] * 2.f + (B[i0][1] + B[i2][1]);
      const v4f gy1 = C[i1][1] * 2.f + (C[i0][1] + C[i2][1]);
      const v4f gz1 = A[i2][1] - A[i0][1];
      const v4f q1 = gx1 * gx1 + gy1 * gy1 + gz1 * gz1 + EPS;
      v4f dd_;
#pragma unroll
      for (int j = 0; j < 4; ++j)
        dd_[j] = __builtin_amdgcn_sqrtf(q0[j]) - __builtin_amdgcn_sqrtf(q1[j]);
#pragma unroll
      for (int j = 0; j < 4; ++j) dd_[j] = fabsf(dd_[j]);
      accv += dd_;
    }
    __syncthreads();            // barrier 2: drain of GLOAD covered by compute
  }

  // ---- reduction: wave shfl -> LDS -> one atomic per block ----
  float sred = accv.x + accv.y + accv.z + accv.w;
#pragma unroll
  for (int off = 32; off > 0; off >>= 1) sred += __shfl_down(sred, off, 64);
  __shared__ float wsum[THREADS / 64];
  const int wid = tid >> 6;
  if (lane == 0) wsum[wid] = sred;
  __syncthreads();
  if (tid == 0) {
    float t = 0.f;
#pragma unroll
    for (int i = 0; i < THREADS / 64; ++i) t += wsum[i];
    atomicAdd(out, t * (1.0f / (float)((size_t)Bd * Dd * Hd * Wd)));
  }
}

extern "C" void kernel_launch(void* const* d_in, const int* in_sizes, int n_in,
                              void* d_out, int out_size, void* d_ws, size_t ws_size,
                              hipStream_t stream) {
  const float* pred = (const float*)d_in[0];
  const float* targ = (const float*)d_in[1];
  float* out = (float*)d_out;
  (void)in_sizes; (void)n_in; (void)out_size; (void)d_ws; (void)ws_size;

  hipMemsetAsync(out, 0, sizeof(float), stream);
  dim3 grid(RGROUPS, NCHUNK, Bd);
  sobel_loss_kernel<<<grid, THREADS, 0, stream>>>(pred, targ, out);
}